// Round 6
// baseline (192.707 us; speedup 1.0000x reference)
//
#include <hip/hip_runtime.h>
#include <hip/hip_bf16.h>

// ---------------------------------------------------------------------------
// SemanticActor fused forward, bf16 MFMA (gfx950) — Round 6
// R5 diagnosis: pipes serialized (MFMA 36us + LDS ~40us + VALU ~32us ~= 117us
// measured): 1 block/CU, all waves phase-locked by barriers. Body needs only
// 108 VGPR -> fits the 128 cap of launch_bounds(512,2) (2 blocks/CU in this
// toolchain, CUDA-style min-blocks semantics, evidence: R4 capped at 128).
// Sole change vs R5: launch_bounds (512,1) -> (512,2) for 2 co-resident,
// phase-desynchronized blocks per CU. Watch WRITE_SIZE for spill regression.
// ---------------------------------------------------------------------------

#define B_TOTAL 65536
#define TROWS   64
#define RSTR    136   // rawS row stride elems: 272 B = 17x16B (odd) -> <=2-way

typedef __attribute__((ext_vector_type(8))) short s8v;   // 8 x bf16
typedef __attribute__((ext_vector_type(4))) float f4v;   // MFMA C/D

__constant__ int c_PI[6] = {0,0,1,1,2,2};
__constant__ int c_PJ[6] = {1,2,0,2,0,1};
__constant__ int c_PF[6] = {0,0,1,0,1,1};
// inverse of FIRST_INDS / SECOND_INDS: raw ag/g col -> X col (or -1)
__constant__ int c_INV[2][30] = {
  {0,1,2,3,4,5,6,7,8,9,10,11,12,13,-1,14,15,16,-1,-1,17,18,-1,-1,-1,19,-1,-1,-1,-1},
  {0,1,2,3,4,5,6,7,8,9,-1,-1,-1,-1,10,-1,-1,-1,11,12,-1,-1,13,14,15,-1,16,17,18,19}};

__global__ void prep_weights(const float* __restrict__ phi_w1,
                             const float* __restrict__ phi_b1,
                             const float* __restrict__ phi_w2,
                             const float* __restrict__ rho_w1,
                             const float* __restrict__ mean_w,
                             const float* __restrict__ logstd_w,
                             __hip_bfloat16* __restrict__ W1P,
                             __hip_bfloat16* __restrict__ W2f,
                             __hip_bfloat16* __restrict__ W3f,
                             __hip_bfloat16* __restrict__ W4f) {
  const int i0 = blockIdx.x * blockDim.x + threadIdx.x;
  const int stride = gridDim.x * blockDim.x;
  // W1P: 6 pairs x (16 nb x 4 ks) x 512; K=128 raw cols via inverse map
  for (int d = i0; d < 6 * 32768; d += stride) {
    int p = d >> 15, r = d & 32767;
    int j = r & 7, lane = (r >> 3) & 63, blk = r >> 9;
    int nb = blk >> 2, ks = blk & 3;
    int n = nb * 16 + (lane & 15), k = ks * 32 + (lane >> 4) * 8 + j;
    int f = c_PF[p], oi = c_PI[p], oj = c_PJ[p];
    float v = 0.0f;
    if (k < 30)       { int t = c_INV[f][k];      if (t >= 0) v = phi_w1[t * 256 + n]; }
    else if (k < 60)  { int t = c_INV[f][k - 30]; if (t >= 0) v = phi_w1[(30 + t) * 256 + n]; }
    else if (k < 70)  { v = phi_w1[(20 + k - 60) * 256 + n]; }
    else if (k < 115) { int q = (k - 70) / 15, t = (k - 70) - q * 15;
                        int c = (q == oi) ? 50 + t : (q == oj) ? 65 + t : -1;
                        if (c >= 0) v = phi_w1[c * 256 + n]; }
    else if (k == 115) v = phi_b1[n];   // bias via ones-column
    W1P[d] = __float2bfloat16(v);
  }
  // W2f/W3f: 16 nb x 8 ks, 256x256
  for (int d = i0; d < 65536; d += stride) {
    int j = d & 7, lane = (d >> 3) & 63, blk = d >> 9;
    int nb = blk >> 3, ks = blk & 7;
    int n = nb * 16 + (lane & 15), k = ks * 32 + (lane >> 4) * 8 + j;
    W2f[d] = __float2bfloat16(phi_w2[k * 256 + n]);
    W3f[d] = __float2bfloat16(rho_w1[k * 256 + n]);
  }
  // W4f: 1 nb (16 head cols: 0-3 mean, 4-7 logstd, rest 0) x 8 ks
  for (int d = i0; d < 4096; d += stride) {
    int j = d & 7, lane = (d >> 3) & 63, ks = d >> 9;
    int n = lane & 15, k = ks * 32 + (lane >> 4) * 8 + j;
    float v = (n < 4) ? mean_w[k * 4 + n]
            : (n < 8) ? logstd_w[k * 4 + (n - 4)] : 0.0f;
    W4f[d] = __float2bfloat16(v);
  }
}

static __device__ __forceinline__ unsigned pk2(float a, float b) {
  __hip_bfloat162 h = __float22bfloat162_rn(float2{a, b});
  union { __hip_bfloat162 h2; unsigned u; } cv; cv.h2 = h;
  return cv.u;
}

// ---- main: 512 threads (8 waves), 64 rows/block, wave = 32-col slice -------
__global__ __launch_bounds__(512, 2)
void actor_main(const float* __restrict__ obs, const float* __restrict__ ag,
                const float* __restrict__ g,
                const __hip_bfloat16* __restrict__ W1P,
                const __hip_bfloat16* __restrict__ W2f,
                const __hip_bfloat16* __restrict__ W3f,
                const __hip_bfloat16* __restrict__ W4f,
                const float* __restrict__ b2, const float* __restrict__ b3,
                const float* __restrict__ meanb,
                const float* __restrict__ logstdb,
                float* __restrict__ out) {
  __shared__ __align__(16) __hip_bfloat16 rawS[TROWS * RSTR];  // 17.4 KB
  __shared__ __align__(16) __hip_bfloat16 Hs[4 * 8 * 512];     // 32 KB

  const int tid  = threadIdx.x;
  const int lane = tid & 63;
  const int w    = tid >> 6;      // wave 0..7 -> hidden cols [32w, 32w+32)
  const int l15  = lane & 15;
  const int quad = lane >> 4;
  const int r0   = blockIdx.x * TROWS;

  float4 b2v[2], b3v[2];
#pragma unroll
  for (int i = 0; i < 2; ++i) {
    int col0 = w * 32 + i * 16 + quad * 4;
    b2v[i] = *(const float4*)&b2[col0];
    b3v[i] = *(const float4*)&b3[col0];
  }

  // persistent W2 fragments (once per block)
  s8v w2f[8][2];
#pragma unroll
  for (int i = 0; i < 2; ++i)
#pragma unroll
    for (int ks = 0; ks < 8; ++ks)
      w2f[ks][i] = *(const s8v*)&W2f[(((w * 2 + i) * 8 + ks) * 512) + lane * 8];

  // stage raw input [ag|g|obs|1|0] as bf16, K=128, once per block
  {
    const int row = tid >> 3;           // 0..63
    const int c0  = (tid & 7) * 16;     // 0..112
    const float* agr = ag  + (size_t)(r0 + row) * 30;
    const float* gr  = g   + (size_t)(r0 + row) * 30;
    const float* obr = obs + (size_t)(r0 + row) * 55;
#pragma unroll
    for (int cc = 0; cc < 16; ++cc) {
      int c = c0 + cc;
      float v;
      if      (c < 30)  v = agr[c];
      else if (c < 60)  v = gr[c - 30];
      else if (c < 115) v = obr[c - 60];
      else if (c == 115) v = 1.0f;
      else              v = 0.0f;
      rawS[row * RSTR + c] = __float2bfloat16(v);
    }
  }

  f4v agg[2][4];
#pragma unroll
  for (int i = 0; i < 2; ++i)
#pragma unroll
    for (int rt = 0; rt < 4; ++rt) agg[i][rt] = f4v{0.f, 0.f, 0.f, 0.f};

  const int ebase = l15 * 8 + (quad >> 1) * 128 + (quad & 1) * 4;

  __syncthreads();  // rawS staged

#pragma unroll 1
  for (int p = 0; p < 6; ++p) {
    // load this pair's W1P frags (L2-resident, used once)
    s8v w1f[4][2];
    {
      const __hip_bfloat16* base = W1P + p * 32768;
#pragma unroll
      for (int i = 0; i < 2; ++i)
#pragma unroll
        for (int ks = 0; ks < 4; ++ks)
          w1f[ks][i] = *(const s8v*)&base[(((w * 2 + i) * 4 + ks) * 512) + lane * 8];
    }

    // GEMM1: h = W1P[p](A) x raw(B); K=128
    f4v h[2][4];
#pragma unroll
    for (int i = 0; i < 2; ++i)
#pragma unroll
      for (int rt = 0; rt < 4; ++rt) h[i][rt] = f4v{0.f, 0.f, 0.f, 0.f};
#pragma unroll
    for (int ks = 0; ks < 4; ++ks) {
      s8v bx[4];
#pragma unroll
      for (int rt = 0; rt < 4; ++rt)
        bx[rt] = *(const s8v*)&rawS[(rt * 16 + l15) * RSTR + ks * 32 + quad * 8];
#pragma unroll
      for (int i = 0; i < 2; ++i)
#pragma unroll
        for (int rt = 0; rt < 4; ++rt)
          h[i][rt] = __builtin_amdgcn_mfma_f32_16x16x32_bf16(w1f[ks][i], bx[rt], h[i][rt], 0, 0, 0);
    }

    __syncthreads();  // prior GEMM2 Hs reads complete
    // epilogue: relu only (bias folded into ones-column), pack -> b64 write
#pragma unroll
    for (int i = 0; i < 2; ++i)
#pragma unroll
      for (int rt = 0; rt < 4; ++rt) {
        float v0 = fmaxf(h[i][rt][0], 0.f);
        float v1 = fmaxf(h[i][rt][1], 0.f);
        float v2 = fmaxf(h[i][rt][2], 0.f);
        float v3 = fmaxf(h[i][rt][3], 0.f);
        uint2 U; U.x = pk2(v0, v1); U.y = pk2(v2, v3);
        *reinterpret_cast<uint2*>(&Hs[(rt * 8 + w) * 512 + i * 256 + ebase]) = U;
      }
    __syncthreads();

    // GEMM2: a2 = W2(A) x H(B); K=256; agg += relu(a2 + b2)
    f4v a2[2][4];
#pragma unroll
    for (int i = 0; i < 2; ++i)
#pragma unroll
      for (int rt = 0; rt < 4; ++rt) a2[i][rt] = f4v{0.f, 0.f, 0.f, 0.f};
#pragma unroll
    for (int ks = 0; ks < 8; ++ks) {
      s8v hf[4];
#pragma unroll
      for (int rt = 0; rt < 4; ++rt)
        hf[rt] = *(const s8v*)&Hs[(rt * 8 + ks) * 512 + lane * 8];
#pragma unroll
      for (int i = 0; i < 2; ++i)
#pragma unroll
        for (int rt = 0; rt < 4; ++rt)
          a2[i][rt] = __builtin_amdgcn_mfma_f32_16x16x32_bf16(w2f[ks][i], hf[rt], a2[i][rt], 0, 0, 0);
    }
#pragma unroll
    for (int i = 0; i < 2; ++i)
#pragma unroll
      for (int rt = 0; rt < 4; ++rt) {
        agg[i][rt][0] += fmaxf(a2[i][rt][0] + b2v[i].x, 0.f);
        agg[i][rt][1] += fmaxf(a2[i][rt][1] + b2v[i].y, 0.f);
        agg[i][rt][2] += fmaxf(a2[i][rt][2] + b2v[i].z, 0.f);
        agg[i][rt][3] += fmaxf(a2[i][rt][3] + b2v[i].w, 0.f);
      }
  }

  // W3 frags (w2f dead, registers reused)
  s8v w3f[8][2];
#pragma unroll
  for (int i = 0; i < 2; ++i)
#pragma unroll
    for (int ks = 0; ks < 8; ++ks)
      w3f[ks][i] = *(const s8v*)&W3f[(((w * 2 + i) * 8 + ks) * 512) + lane * 8];

  __syncthreads();  // all GEMM2 Hs reads done
#pragma unroll
  for (int i = 0; i < 2; ++i)
#pragma unroll
    for (int rt = 0; rt < 4; ++rt) {
      uint2 U; U.x = pk2(agg[i][rt][0], agg[i][rt][1]);
      U.y = pk2(agg[i][rt][2], agg[i][rt][3]);
      *reinterpret_cast<uint2*>(&Hs[(rt * 8 + w) * 512 + i * 256 + ebase]) = U;
    }
  __syncthreads();

  // GEMM3: hr = relu(W3(A) x agg(B) + b3); K=256
  f4v a3[2][4];
#pragma unroll
  for (int i = 0; i < 2; ++i)
#pragma unroll
    for (int rt = 0; rt < 4; ++rt) a3[i][rt] = f4v{0.f, 0.f, 0.f, 0.f};
#pragma unroll
  for (int ks = 0; ks < 8; ++ks) {
    s8v hf[4];
#pragma unroll
    for (int rt = 0; rt < 4; ++rt)
      hf[rt] = *(const s8v*)&Hs[(rt * 8 + ks) * 512 + lane * 8];
#pragma unroll
    for (int i = 0; i < 2; ++i)
#pragma unroll
      for (int rt = 0; rt < 4; ++rt)
        a3[i][rt] = __builtin_amdgcn_mfma_f32_16x16x32_bf16(w3f[ks][i], hf[rt], a3[i][rt], 0, 0, 0);
  }
  __syncthreads();
#pragma unroll
  for (int i = 0; i < 2; ++i)
#pragma unroll
    for (int rt = 0; rt < 4; ++rt) {
      float v0 = fmaxf(a3[i][rt][0] + b3v[i].x, 0.f);
      float v1 = fmaxf(a3[i][rt][1] + b3v[i].y, 0.f);
      float v2 = fmaxf(a3[i][rt][2] + b3v[i].z, 0.f);
      float v3 = fmaxf(a3[i][rt][3] + b3v[i].w, 0.f);
      uint2 U; U.x = pk2(v0, v1); U.y = pk2(v2, v3);
      *reinterpret_cast<uint2*>(&Hs[(rt * 8 + w) * 512 + i * 256 + ebase]) = U;
    }
  __syncthreads();

  // GEMM4: heads; waves 0..3 take batch tile rt=w
  if (w < 4) {
    f4v a4 = f4v{0.f, 0.f, 0.f, 0.f};
#pragma unroll
    for (int ks = 0; ks < 8; ++ks) {
      s8v w4 = *(const s8v*)&W4f[ks * 512 + lane * 8];
      s8v hf = *(const s8v*)&Hs[(w * 8 + ks) * 512 + lane * 8];
      a4 = __builtin_amdgcn_mfma_f32_16x16x32_bf16(w4, hf, a4, 0, 0, 0);
    }
    const int row = r0 + w * 16 + l15;
    if (quad == 0) {          // head cols 0..3 = mean
      float4 mb = *(const float4*)meanb;
      float4 o;
      o.x = a4[0] + mb.x; o.y = a4[1] + mb.y;
      o.z = a4[2] + mb.z; o.w = a4[3] + mb.w;
      *reinterpret_cast<float4*>(&out[(size_t)row * 4]) = o;
    } else if (quad == 1) {   // head cols 4..7 = logstd (clipped)
      float4 lb = *(const float4*)logstdb;
      float4 o;
      o.x = fminf(fmaxf(a4[0] + lb.x, -20.f), 2.f);
      o.y = fminf(fmaxf(a4[1] + lb.y, -20.f), 2.f);
      o.z = fminf(fmaxf(a4[2] + lb.z, -20.f), 2.f);
      o.w = fminf(fmaxf(a4[3] + lb.w, -20.f), 2.f);
      *reinterpret_cast<float4*>(&out[(size_t)B_TOTAL * 4 + (size_t)row * 4]) = o;
    }
  }
}

extern "C" void kernel_launch(void* const* d_in, const int* in_sizes, int n_in,
                              void* d_out, int out_size, void* d_ws, size_t ws_size,
                              hipStream_t stream) {
  const float* obs      = (const float*)d_in[0];
  const float* ag       = (const float*)d_in[1];
  const float* g        = (const float*)d_in[2];
  const float* phi_w1   = (const float*)d_in[3];
  const float* phi_b1   = (const float*)d_in[4];
  const float* phi_w2   = (const float*)d_in[5];
  const float* phi_b2   = (const float*)d_in[6];
  const float* rho_w1   = (const float*)d_in[7];
  const float* rho_b1   = (const float*)d_in[8];
  const float* mean_w   = (const float*)d_in[9];
  const float* mean_b   = (const float*)d_in[10];
  const float* logstd_w = (const float*)d_in[11];
  const float* logstd_b = (const float*)d_in[12];
  float* out = (float*)d_out;

  // ws (bf16): W1P 6x32768 | W2f 65536 | W3f 65536 | W4f 4096 elems
  char* ws = (char*)d_ws;
  __hip_bfloat16* W1P = (__hip_bfloat16*)(ws);
  __hip_bfloat16* W2f = (__hip_bfloat16*)(ws + 393216);
  __hip_bfloat16* W3f = (__hip_bfloat16*)(ws + 393216 + 131072);
  __hip_bfloat16* W4f = (__hip_bfloat16*)(ws + 393216 + 262144);

  prep_weights<<<256, 256, 0, stream>>>(phi_w1, phi_b1, phi_w2, rho_w1,
                                        mean_w, logstd_w, W1P, W2f, W3f, W4f);
  actor_main<<<B_TOTAL / TROWS, 512, 0, stream>>>(
      obs, ag, g, W1P, W2f, W3f, W4f, phi_b2, rho_b1, mean_b, logstd_b, out);
}